// Round 2
// baseline (184.372 us; speedup 1.0000x reference)
//
#include <hip/hip_runtime.h>
#include <hip/hip_bf16.h>
#include <math.h>

// Problem constants: B=1, T=2048, C=512, NH=8, NKV=4, HD=64, W=128
#define TT   2048
#define CC   512
#define NHQ  8
#define NKVH 4
#define HDIM 64
#define WIN  128

// ---------------------------------------------------------------------------
// Tiled f32 GEMM: C[M x N] = A[M x K] @ B[K x N]; 64x64 tile per 256-thread
// block, 4x4 microtile per thread, K-step 16. lda=K, ldb=N, ldc passed in.
// M comes from gridDim.y * 64 (all dims here are multiples of 64/16).
// ---------------------------------------------------------------------------
__global__ __launch_bounds__(256) void gemm64(const float* __restrict__ A,
    const float* __restrict__ B, float* __restrict__ C,
    int N, int ldc, int K)
{
    __shared__ float As[16][68];   // transposed: As[k][m]; 68*4B=272=16*17 keeps 16B align
    __shared__ float Bs[16][64];   // natural: Bs[k][n]
    const int tid = threadIdx.x;
    const int m0 = blockIdx.y * 64, n0 = blockIdx.x * 64;
    const int ty = tid >> 4, tx = tid & 15;
    const int arow = tid >> 2, ak = (tid & 3) * 4;   // A loader
    const int brow = tid >> 4, bc = (tid & 15) * 4;  // B loader
    float acc[4][4] = {};
    for (int k0 = 0; k0 < K; k0 += 16) {
        float4 a4 = *(const float4*)(A + (size_t)(m0 + arow) * K + k0 + ak);
        float4 b4 = *(const float4*)(B + (size_t)(k0 + brow) * N + n0 + bc);
        __syncthreads();   // previous iteration's reads done before overwrite
        As[ak+0][arow] = a4.x; As[ak+1][arow] = a4.y;
        As[ak+2][arow] = a4.z; As[ak+3][arow] = a4.w;
        *(float4*)&Bs[brow][bc] = b4;
        __syncthreads();
#pragma unroll
        for (int kk = 0; kk < 16; ++kk) {
            float4 av = *(const float4*)&As[kk][ty * 4];
            float4 bv = *(const float4*)&Bs[kk][tx * 4];
            float a[4] = {av.x, av.y, av.z, av.w};
            float b[4] = {bv.x, bv.y, bv.z, bv.w};
#pragma unroll
            for (int i = 0; i < 4; ++i)
#pragma unroll
                for (int j = 0; j < 4; ++j)
                    acc[i][j] = fmaf(a[i], b[j], acc[i][j]);
        }
    }
#pragma unroll
    for (int i = 0; i < 4; ++i)
#pragma unroll
        for (int j = 0; j < 4; ++j)
            C[(size_t)(m0 + ty*4 + i) * ldc + n0 + tx*4 + j] = acc[i][j];
}

// ---------------------------------------------------------------------------
// Fused RoPE (pairs d, d+32) + RMSNorm (over 64 dims, applied AFTER rope,
// matching the reference order). One wave per (t, head): heads 0..7 = q,
// 8..11 = k. v untouched. qkv layout: [T][1024] = [q(512) | k(256) | v(256)]
// ---------------------------------------------------------------------------
__global__ __launch_bounds__(256) void rope_rms(const float* __restrict__ qkv,
    const float* __restrict__ cosT, const float* __restrict__ sinT,
    const float* __restrict__ qw, const float* __restrict__ kw,
    float* __restrict__ qn, float* __restrict__ kn)
{
    const int tid  = threadIdx.x;
    const int lane = tid & 63;
    const int gid  = blockIdx.x * 4 + (tid >> 6);
    const int t    = gid / 12;
    const int hh   = gid % 12;
    const float* src; float* dst; const float* nw;
    if (hh < NHQ) {
        src = qkv + (size_t)t * 1024 + hh * HDIM;
        dst = qn  + (size_t)t * 512  + hh * HDIM;
        nw  = qw;
    } else {
        int kvh = hh - NHQ;
        src = qkv + (size_t)t * 1024 + 512 + kvh * HDIM;
        dst = kn  + (size_t)t * 256  + kvh * HDIM;
        nw  = kw;
    }
    float y = src[lane];
    float o = __shfl(y, lane ^ 32);
    float c = cosT[t * 32 + (lane & 31)];
    float s = sinT[t * 32 + (lane & 31)];
    float r = (lane < 32) ? (y * c - o * s) : (y * c + o * s);
    float ss = r * r;
#pragma unroll
    for (int off = 32; off; off >>= 1) ss += __shfl_xor(ss, off);
    float scale = rsqrtf(ss * (1.0f / 64.0f) + 1e-6f);
    dst[lane] = r * scale * nw[lane];
}

// ---------------------------------------------------------------------------
// Sliding-window attention. Block = (head h, 64-query tile t0). Stages the
// 192-row K/V window [t0-127, t0+63] into LDS (stride 65: 2-way bank alias =
// free per m136). Wave handles 16 queries; per query each lane owns keys
// w=lane and w=lane+64 of the 128-wide window; softmax via shfl-xor reduce;
// PV via shfl-broadcast of unnormalized p, final scale by 1/sum.
// ---------------------------------------------------------------------------
__global__ __launch_bounds__(256) void swa_attn(const float* __restrict__ qn,
    const float* __restrict__ kn, const float* __restrict__ qkv,
    float* __restrict__ att)
{
    __shared__ float Ks[192][65];
    __shared__ float Vs[192][65];
    const int tid = threadIdx.x;
    const int h   = blockIdx.y;
    const int kvh = h >> 1;              // GQA: jnp.repeat -> kv head = h // 2
    const int t0  = blockIdx.x * 64;
    for (int idx = tid; idx < 192 * 16; idx += 256) {
        int j  = idx >> 4;
        int c4 = (idx & 15) * 4;
        int kt = t0 - 127 + j;
        float4 kv = {0.f, 0.f, 0.f, 0.f}, vv = {0.f, 0.f, 0.f, 0.f};
        if (kt >= 0) {
            kv = *(const float4*)(kn  + (size_t)kt * 256  + kvh * HDIM + c4);
            vv = *(const float4*)(qkv + (size_t)kt * 1024 + 768 + kvh * HDIM + c4);
        }
        Ks[j][c4+0] = kv.x; Ks[j][c4+1] = kv.y; Ks[j][c4+2] = kv.z; Ks[j][c4+3] = kv.w;
        Vs[j][c4+0] = vv.x; Vs[j][c4+1] = vv.y; Vs[j][c4+2] = vv.z; Vs[j][c4+3] = vv.w;
    }
    __syncthreads();
    const int wv = tid >> 6, lane = tid & 63;
    for (int ii = 0; ii < 16; ++ii) {
        const int qi = wv * 16 + ii;
        const int t  = t0 + qi;
        const int tU = __builtin_amdgcn_readfirstlane(t);
        const float* qrow = qn + (size_t)tU * 512 + h * HDIM;  // wave-uniform -> s_loads
        float acc0 = 0.f, acc1 = 0.f;
        const float* kp0 = &Ks[qi + lane][0];
        const float* kp1 = &Ks[qi + 64 + lane][0];
#pragma unroll
        for (int d = 0; d < 64; ++d) {
            float qd = qrow[d];
            acc0 = fmaf(qd, kp0[d], acc0);
            acc1 = fmaf(qd, kp1[d], acc1);
        }
        // key positions: kt0 = t-127+lane, kt1 = t-63+lane; mask kt<0
        bool v0 = (t - 127 + lane) >= 0;
        bool v1 = (t - 63  + lane) >= 0;
        float s0 = v0 ? acc0 * 0.125f : -INFINITY;
        float s1 = v1 ? acc1 * 0.125f : -INFINITY;
        float m = fmaxf(s0, s1);
#pragma unroll
        for (int off = 32; off; off >>= 1) m = fmaxf(m, __shfl_xor(m, off));
        float p0 = v0 ? __expf(s0 - m) : 0.f;
        float p1 = v1 ? __expf(s1 - m) : 0.f;
        float sum = p0 + p1;
#pragma unroll
        for (int off = 32; off; off >>= 1) sum += __shfl_xor(sum, off);
        float inv = 1.0f / sum;
        float oacc = 0.f;
#pragma unroll
        for (int w = 0; w < 64; ++w)
            oacc = fmaf(__shfl(p0, w), Vs[qi + w][lane], oacc);
#pragma unroll
        for (int w = 0; w < 64; ++w)
            oacc = fmaf(__shfl(p1, w), Vs[qi + 64 + w][lane], oacc);
        att[(size_t)t * 512 + h * HDIM + lane] = oacc * inv;
    }
}

// ---------------------------------------------------------------------------
// Orchestration. Workspace (f32):
//   qkv [2048*1024] | qn [2048*512] | kn [2048*256] | att [2048*512]  = 18 MB
// Output: float32 (reference returns f32).
// ---------------------------------------------------------------------------
extern "C" void kernel_launch(void* const* d_in, const int* in_sizes, int n_in,
                              void* d_out, int out_size, void* d_ws, size_t ws_size,
                              hipStream_t stream)
{
    const float* x    = (const float*)d_in[0];
    const float* Wq   = (const float*)d_in[1];
    const float* Wk   = (const float*)d_in[2];
    const float* Wv   = (const float*)d_in[3];
    const float* Wo   = (const float*)d_in[4];
    const float* qw   = (const float*)d_in[5];
    const float* kw   = (const float*)d_in[6];
    const float* cosT = (const float*)d_in[7];
    const float* sinT = (const float*)d_in[8];

    float* ws  = (float*)d_ws;
    float* qkv = ws;                          // 2048*1024
    float* qn  = qkv + (size_t)2048 * 1024;   // 2048*512
    float* kn  = qn  + (size_t)2048 * 512;    // 2048*256
    float* att = kn  + (size_t)2048 * 256;    // 2048*512

    dim3 blk(256);
    // QKV projections into the concatenated qkv buffer (ldc = 1024)
    hipLaunchKernelGGL(gemm64, dim3(8, 32), blk, 0, stream,
                       x, Wq, qkv,       512, 1024, 512);
    hipLaunchKernelGGL(gemm64, dim3(4, 32), blk, 0, stream,
                       x, Wk, qkv + 512, 256, 1024, 512);
    hipLaunchKernelGGL(gemm64, dim3(4, 32), blk, 0, stream,
                       x, Wv, qkv + 768, 256, 1024, 512);
    // RoPE + RMS for q and k heads (v passes through, read directly from qkv)
    hipLaunchKernelGGL(rope_rms, dim3(2048 * 12 / 4), blk, 0, stream,
                       qkv, cosT, sinT, qw, kw, qn, kn);
    // Sliding-window attention
    hipLaunchKernelGGL(swa_attn, dim3(32, 8), blk, 0, stream, qn, kn, qkv, att);
    // Output projection -> f32 (reference output dtype)
    hipLaunchKernelGGL(gemm64, dim3(8, 32), blk, 0, stream,
                       att, Wo, (float*)d_out, 512, 512, 512);
}

// Round 3
// 42.004 us; speedup vs baseline: 4.3894x; 4.3894x over previous
//
#include <hip/hip_runtime.h>
#include <hip/hip_bf16.h>
#include <math.h>

typedef float  f32x4  __attribute__((ext_vector_type(4)));
typedef short  s16x4  __attribute__((ext_vector_type(4)));
typedef short  s16x8  __attribute__((ext_vector_type(8)));
typedef unsigned short u16;

__device__ inline u16 f2b(float f) {
    __hip_bfloat16 h = __float2bfloat16(f);
    return *reinterpret_cast<u16*>(&h);
}

// ---------------------------------------------------------------------------
// Prep 1: cast x (2048x512 f32) -> bf16. grid 1024 x 256, 4 elems/thread.
// ---------------------------------------------------------------------------
__global__ __launch_bounds__(256) void cast_x(const float* __restrict__ x,
                                              u16* __restrict__ xb)
{
    int i = (blockIdx.x * 256 + threadIdx.x) * 4;
    float4 v = *(const float4*)(x + i);
    ushort4 o = { f2b(v.x), f2b(v.y), f2b(v.z), f2b(v.w) };
    *(ushort4*)(xb + i) = o;
}

// ---------------------------------------------------------------------------
// Prep 2: transpose-cast weights to B^T bf16 layout.
//   Wt  [1024][512]: rows 0-511 = Wq^T, 512-767 = Wk^T, 768-1023 = Wv^T
//   Wot [512][512]  = Wo^T
// 64x64 tiles via LDS. 192 blocks.
// ---------------------------------------------------------------------------
__global__ __launch_bounds__(256) void prep_transpose(const float* __restrict__ Wq,
    const float* __restrict__ Wk, const float* __restrict__ Wv,
    const float* __restrict__ Wo, u16* __restrict__ Wt, u16* __restrict__ Wot)
{
    __shared__ u16 Tsh[64][72];
    const int tid = threadIdx.x, bid = blockIdx.x;
    const float* src; u16* dst; int N, base, kt, nt;
    if (bid < 64)       { src = Wq; dst = Wt;  N = 512; base = 0;   kt = bid >> 3;        nt = bid & 7; }
    else if (bid < 96)  { src = Wk; dst = Wt;  N = 256; base = 512; kt = (bid-64) >> 2;   nt = (bid-64) & 3; }
    else if (bid < 128) { src = Wv; dst = Wt;  N = 256; base = 768; kt = (bid-96) >> 2;   nt = (bid-96) & 3; }
    else                { src = Wo; dst = Wot; N = 512; base = 0;   kt = (bid-128) >> 3;  nt = (bid-128) & 7; }
    const int k0 = kt * 64, n0 = nt * 64;
    const int r = tid >> 2, c0 = (tid & 3) * 16;
#pragma unroll
    for (int j = 0; j < 4; ++j) {
        float4 v = *(const float4*)(src + (size_t)(k0 + r) * N + n0 + c0 + j * 4);
        Tsh[c0 + j*4 + 0][r] = f2b(v.x);
        Tsh[c0 + j*4 + 1][r] = f2b(v.y);
        Tsh[c0 + j*4 + 2][r] = f2b(v.z);
        Tsh[c0 + j*4 + 3][r] = f2b(v.w);
    }
    __syncthreads();
    const int n = tid >> 2, kc = (tid & 3) * 16;
    u16* op = dst + (size_t)(base + n0 + n) * 512 + k0 + kc;
    *(s16x8*)(op)     = *(const s16x8*)&Tsh[n][kc];
    *(s16x8*)(op + 8) = *(const s16x8*)&Tsh[n][kc + 8];
}

// ---------------------------------------------------------------------------
// bf16 MFMA GEMM: C[M x N] f32 = A[M x 512] bf16 @ B (given as Bt[N][512] bf16).
// 64x64 tile / 256 threads / 4 waves; wave = 32x32 (2x2 16-tiles), BK=64.
// A-frag: lane m=l&15, k=(l>>4)*8+i (ds_read_b128, pad-72 rows = even banks).
// ---------------------------------------------------------------------------
__global__ __launch_bounds__(256) void gemm_mfma(const u16* __restrict__ A,
    const u16* __restrict__ Bt, float* __restrict__ C, int N, int ldc)
{
    __shared__ u16 Ash[64][72];
    __shared__ u16 Bsh[64][72];
    const int tid = threadIdx.x;
    const int m0b = blockIdx.y * 64, n0b = blockIdx.x * 64;
    const int lane = tid & 63, wv = tid >> 6;
    const int q = lane & 15, g = lane >> 4;
    const int wm = (wv & 1) * 32, wn = (wv >> 1) * 32;
    const int sr = tid >> 2, sc = (tid & 3) * 16;
    f32x4 acc[2][2] = {{{0,0,0,0},{0,0,0,0}},{{0,0,0,0},{0,0,0,0}}};
    for (int k0 = 0; k0 < 512; k0 += 64) {
        s16x8 a0 = *(const s16x8*)(A  + (size_t)(m0b + sr) * 512 + k0 + sc);
        s16x8 a1 = *(const s16x8*)(A  + (size_t)(m0b + sr) * 512 + k0 + sc + 8);
        s16x8 b0 = *(const s16x8*)(Bt + (size_t)(n0b + sr) * 512 + k0 + sc);
        s16x8 b1 = *(const s16x8*)(Bt + (size_t)(n0b + sr) * 512 + k0 + sc + 8);
        __syncthreads();
        *(s16x8*)&Ash[sr][sc]     = a0;
        *(s16x8*)&Ash[sr][sc + 8] = a1;
        *(s16x8*)&Bsh[sr][sc]     = b0;
        *(s16x8*)&Bsh[sr][sc + 8] = b1;
        __syncthreads();
#pragma unroll
        for (int kk = 0; kk < 64; kk += 32) {
            s16x8 af0 = *(const s16x8*)&Ash[wm + q][kk + g*8];
            s16x8 af1 = *(const s16x8*)&Ash[wm + 16 + q][kk + g*8];
            s16x8 bf0 = *(const s16x8*)&Bsh[wn + q][kk + g*8];
            s16x8 bf1 = *(const s16x8*)&Bsh[wn + 16 + q][kk + g*8];
            acc[0][0] = __builtin_amdgcn_mfma_f32_16x16x32_bf16(af0, bf0, acc[0][0], 0, 0, 0);
            acc[0][1] = __builtin_amdgcn_mfma_f32_16x16x32_bf16(af0, bf1, acc[0][1], 0, 0, 0);
            acc[1][0] = __builtin_amdgcn_mfma_f32_16x16x32_bf16(af1, bf0, acc[1][0], 0, 0, 0);
            acc[1][1] = __builtin_amdgcn_mfma_f32_16x16x32_bf16(af1, bf1, acc[1][1], 0, 0, 0);
        }
    }
#pragma unroll
    for (int mt = 0; mt < 2; ++mt)
#pragma unroll
        for (int nt = 0; nt < 2; ++nt)
#pragma unroll
            for (int r = 0; r < 4; ++r)
                C[(size_t)(m0b + wm + mt*16 + g*4 + r) * ldc + n0b + wn + nt*16 + q] = acc[mt][nt][r];
}

// ---------------------------------------------------------------------------
// RoPE + RMS -> bf16 Q/K; V cast -> bf16. One wave per (t, unit); units:
// 0-7 q-heads, 8-11 k-heads, 12-15 v-cast. qkv f32 [T][1024] = q|k|v.
// ---------------------------------------------------------------------------
__global__ __launch_bounds__(256) void rope_rms_b(const float* __restrict__ qkv,
    const float* __restrict__ cosT, const float* __restrict__ sinT,
    const float* __restrict__ qw, const float* __restrict__ kw,
    u16* __restrict__ qnb, u16* __restrict__ knb, u16* __restrict__ vb)
{
    const int lane = threadIdx.x & 63;
    const int gid  = blockIdx.x * 4 + (threadIdx.x >> 6);
    const int t = gid >> 4, hh = gid & 15;
    if (hh >= 12) {
        int vh = hh - 12;
        vb[(size_t)t * 256 + vh * 64 + lane] =
            f2b(qkv[(size_t)t * 1024 + 768 + vh * 64 + lane]);
        return;
    }
    const float* src; u16* dst; const float* nw;
    if (hh < 8) { src = qkv + (size_t)t*1024 + hh*64;        dst = qnb + (size_t)t*512 + hh*64;       nw = qw; }
    else        { src = qkv + (size_t)t*1024 + 512 + (hh-8)*64; dst = knb + (size_t)t*256 + (hh-8)*64; nw = kw; }
    float y = src[lane];
    float o = __shfl(y, lane ^ 32);
    float c = cosT[t * 32 + (lane & 31)];
    float s = sinT[t * 32 + (lane & 31)];
    float r = (lane < 32) ? (y * c - o * s) : (y * c + o * s);
    float ss = r * r;
#pragma unroll
    for (int off = 32; off; off >>= 1) ss += __shfl_xor(ss, off);
    dst[lane] = f2b(r * rsqrtf(ss * (1.0f/64.0f) + 1e-6f) * nw[lane]);
}

// ---------------------------------------------------------------------------
// MFMA sliding-window attention. Block = (h, 64-q tile), 4 waves x 16 q.
// S^T = K · Q^T via 16x16x32 bf16 (A=K rows natural, B=Q rows natural).
// S^T output rows (w=(l>>4)*4+r) == 16x16x16 operand k-layout, so softmaxed
// P^T feeds O^T = V^T · P^T (A = transposed-V LDS) with no shuffles.
// ---------------------------------------------------------------------------
__global__ __launch_bounds__(256) void swa_mfma(const u16* __restrict__ qnb,
    const u16* __restrict__ knb, const u16* __restrict__ vb,
    u16* __restrict__ attb)
{
    __shared__ u16 Ksh[192][72];   // K rows [window j][d], pad 72
    __shared__ u16 Vt[64][200];    // V^T [d][window j], pad 200
    const int tid = threadIdx.x;
    const int h = blockIdx.y, kvh = h >> 1;
    const int t0 = blockIdx.x * 64;
    // stage K (natural rows)
    for (int i = 0; i < 6; ++i) {
        int idx = i * 256 + tid;
        int j = idx >> 3, d0 = (idx & 7) * 8;
        int kt = t0 - 127 + j;
        s16x8 val = {0,0,0,0,0,0,0,0};
        if (kt >= 0) val = *(const s16x8*)(knb + (size_t)kt * 256 + kvh * 64 + d0);
        *(s16x8*)&Ksh[j][d0] = val;
    }
    // stage V transposed
    for (int cch = 0; cch < 6; ++cch) {
        int w  = cch * 32 + (tid & 31);
        int d0 = (tid >> 5) * 8;
        int kt = t0 - 127 + w;
        s16x8 val = {0,0,0,0,0,0,0,0};
        if (kt >= 0) val = *(const s16x8*)(vb + (size_t)kt * 256 + kvh * 64 + d0);
#pragma unroll
        for (int jj = 0; jj < 8; ++jj) Vt[d0 + jj][w] = ((const u16*)&val)[jj];
    }
    __syncthreads();
    const int wv = tid >> 6, lane = tid & 63;
    const int q = lane & 15, g = lane >> 4;
    const int tw = t0 + wv * 16;
    const int t = tw + q;
    // Q fragments (B-operand): lane n=q, k=d=g*8+i (+32 for second half)
    const u16* qp = qnb + (size_t)t * 512 + h * 64;
    s16x8 qf0 = *(const s16x8*)(qp + g * 8);
    s16x8 qf1 = *(const s16x8*)(qp + 32 + g * 8);
    float s[9][4];
    float mx = -INFINITY;
    for (int wt = 0; wt < 9; ++wt) {
        int ldsrow = wv * 16 + wt * 16 + q;    // A-frag row (w = l&15)
        s16x8 kf0 = *(const s16x8*)&Ksh[ldsrow][g * 8];
        s16x8 kf1 = *(const s16x8*)&Ksh[ldsrow][32 + g * 8];
        f32x4 accv = {0, 0, 0, 0};
        accv = __builtin_amdgcn_mfma_f32_16x16x32_bf16(kf0, qf0, accv, 0, 0, 0);
        accv = __builtin_amdgcn_mfma_f32_16x16x32_bf16(kf1, qf1, accv, 0, 0, 0);
#pragma unroll
        for (int r = 0; r < 4; ++r) {
            int woff = wt * 16 + g * 4 + r;
            int key  = tw - 127 + woff;
            bool ok = (woff >= q) && (woff <= q + 127) && (key >= 0);
            float sv = ok ? accv[r] * 0.125f : -INFINITY;
            s[wt][r] = sv;
            mx = fmaxf(mx, sv);
        }
    }
    mx = fmaxf(mx, __shfl_xor(mx, 16));
    mx = fmaxf(mx, __shfl_xor(mx, 32));
    float sum = 0.f;
    s16x4 pb[9];
    for (int wt = 0; wt < 9; ++wt) {
#pragma unroll
        for (int r = 0; r < 4; ++r) {
            float p = __expf(s[wt][r] - mx);   // exp(-inf) = 0
            sum += p;
            pb[wt][r] = (short)f2b(p);
        }
    }
    sum += __shfl_xor(sum, 16);
    sum += __shfl_xor(sum, 32);
    float inv = 1.0f / sum;
    // PV: O^T[d][q] tiles via 16x16x16 bf16 (K=16 per w-tile)
    f32x4 oacc[4];
#pragma unroll
    for (int dt = 0; dt < 4; ++dt) {
        f32x4 a = {0, 0, 0, 0};
        for (int wt = 0; wt < 9; ++wt) {
            int col = wv * 16 + wt * 16 + g * 4;
            s16x4 vf = *(const s16x4*)&Vt[dt * 16 + q][col];
            a = __builtin_amdgcn_mfma_f32_16x16x16bf16_1k(vf, pb[wt], a, 0, 0, 0);
        }
        oacc[dt] = a;
    }
    // Epilogue: transpose via LDS (overlay on dead Ksh) then coalesced store
    __syncthreads();                                   // all waves done with K/V
    float (*Osh)[16][68] = (float (*)[16][68])&Ksh[0][0];  // 17408 B < 27648 B
#pragma unroll
    for (int dt = 0; dt < 4; ++dt)
#pragma unroll
        for (int r = 0; r < 4; ++r)
            Osh[wv][q][dt * 16 + g * 4 + r] = oacc[dt][r] * inv;
    __syncthreads();
    const int qq = lane >> 2, dd0 = (lane & 3) * 16;
    u16* op = attb + (size_t)(tw + qq) * 512 + h * 64 + dd0;
#pragma unroll
    for (int jj = 0; jj < 4; ++jj) {
        float4 vvv = *(const float4*)&Osh[wv][qq][dd0 + jj * 4];
        ushort4 ov = { f2b(vvv.x), f2b(vvv.y), f2b(vvv.z), f2b(vvv.w) };
        *(ushort4*)(op + jj * 4) = ov;
    }
}

// ---------------------------------------------------------------------------
// Workspace (17.5 MB):
//  qkv f32 [2048*1024] @0 | xb @8M | Wt @10M | Wot @11M | qnb @11.5M
//  knb @13.5M | vb @14.5M | attb @15.5M
// ---------------------------------------------------------------------------
extern "C" void kernel_launch(void* const* d_in, const int* in_sizes, int n_in,
                              void* d_out, int out_size, void* d_ws, size_t ws_size,
                              hipStream_t stream)
{
    const float* x    = (const float*)d_in[0];
    const float* Wq   = (const float*)d_in[1];
    const float* Wk   = (const float*)d_in[2];
    const float* Wv   = (const float*)d_in[3];
    const float* Wo   = (const float*)d_in[4];
    const float* qw   = (const float*)d_in[5];
    const float* kw   = (const float*)d_in[6];
    const float* cosT = (const float*)d_in[7];
    const float* sinT = (const float*)d_in[8];

    char* ws = (char*)d_ws;
    float* qkv = (float*)(ws);
    u16*   xb  = (u16*)(ws + (8u << 20));
    u16*   Wt  = (u16*)(ws + (10u << 20));
    u16*   Wot = (u16*)(ws + (11u << 20));
    u16*   qnb = (u16*)(ws + (11u << 20) + (512u << 10));
    u16*   knb = (u16*)(ws + (13u << 20) + (512u << 10));
    u16*   vb  = (u16*)(ws + (14u << 20) + (512u << 10));
    u16*   attb= (u16*)(ws + (15u << 20) + (512u << 10));

    dim3 blk(256);
    hipLaunchKernelGGL(cast_x,        dim3(1024), blk, 0, stream, x, xb);
    hipLaunchKernelGGL(prep_transpose, dim3(192), blk, 0, stream, Wq, Wk, Wv, Wo, Wt, Wot);
    hipLaunchKernelGGL(gemm_mfma, dim3(16, 32), blk, 0, stream, xb, Wt, qkv, 1024, 1024);
    hipLaunchKernelGGL(rope_rms_b, dim3(8192), blk, 0, stream,
                       qkv, cosT, sinT, qw, kw, qnb, knb, vb);
    hipLaunchKernelGGL(swa_mfma, dim3(32, 8), blk, 0, stream, qnb, knb, vb, attb);
    hipLaunchKernelGGL(gemm_mfma, dim3(8, 32), blk, 0, stream, attb, Wot, (float*)d_out, 512, 512);
}